// Round 11
// baseline (947.168 us; speedup 1.0000x reference)
//
#include <hip/hip_runtime.h>
#include <hip/hip_bf16.h>
#include <math.h>

#define NODES 73728   // B*T*N = 128*64*9
#define BB    128
#define TT    64
#define NN    9
#define LDX   256
#define E_REAL 203648.0f
#define NARR  33

typedef __hip_bfloat16 bf16;
typedef _Float16 half8 __attribute__((ext_vector_type(8)));
typedef _Float16 half4 __attribute__((ext_vector_type(4)));
typedef float f32x4 __attribute__((ext_vector_type(4)));

__device__ __forceinline__ float bfdec(unsigned short u) {
  return __uint_as_float(((unsigned)u) << 16);
}
__device__ __forceinline__ unsigned short f2bf(float x) {
  bf16 h = __float2bfloat16(x);
  return *(unsigned short*)&h;
}
__device__ __forceinline__ float4 ldbf4(const bf16* p) {  // 8B-aligned
  ushort4 u = *(const ushort4*)p;
  float4 f;
  f.x = bfdec(u.x); f.y = bfdec(u.y); f.z = bfdec(u.z); f.w = bfdec(u.w);
  return f;
}

// ---------------- dtype detector ----------------
__global__ __launch_bounds__(256) void detect_kernel(const unsigned short* __restrict__ raw,
                                                     float* __restrict__ flag) {
  __shared__ float sm[256];
  float mx = 0.f;
  for (int i = threadIdx.x; i < 2048; i += 256) mx = fmaxf(mx, fabsf(bfdec(raw[2 * i])));
  sm[threadIdx.x] = mx;
  __syncthreads();
  for (int s = 128; s > 0; s >>= 1) {
    if (threadIdx.x < s) sm[threadIdx.x] = fmaxf(sm[threadIdx.x], sm[threadIdx.x + s]);
    __syncthreads();
  }
  if (threadIdx.x == 0) flag[0] = (sm[0] > 1000.f) ? 1.f : 0.f;
}

// ---------------- convert all inputs to fp32 params region ----------------
struct CvtArgs { const void* src[NARR]; int size[NARR]; int off[NARR]; };

__global__ __launch_bounds__(256) void convert_kernel(CvtArgs a, const float* __restrict__ flag,
                                                      float* __restrict__ dst) {
  int i = blockIdx.y;
  int sz = a.size[i];
  bool isf32 = flag[0] > 0.5f;
  const float* sf = (const float*)a.src[i];
  const unsigned short* sh = (const unsigned short*)a.src[i];
  float* d = dst + a.off[i];
  for (int j = blockIdx.x * 256 + threadIdx.x; j < sz; j += gridDim.x * 256)
    d[j] = isf32 ? sf[j] : bfdec(sh[j]);
}

// ---------------- f16 shadow of the whole param region ----------------
__global__ __launch_bounds__(256) void tohalf_kernel(const float* __restrict__ prm,
                                                     _Float16* __restrict__ dst, int n) {
  int i = blockIdx.x * 256 + threadIdx.x;
  if (i < n) dst[i] = (_Float16)prm[i];
}

// ---------------- encoder (R9-proven: one block per node, thread d) ----------------
__global__ __launch_bounds__(128) void encoder_simple(const float* __restrict__ nf,
    const float* __restrict__ encW, const float* __restrict__ encb, _Float16* __restrict__ Xh) {
  int v = blockIdx.x, d = threadIdx.x, n = v % NN;
  float f[14];
#pragma unroll
  for (int i = 0; i < 10; i++) f[i] = nf[(size_t)v * 10 + i];
  f[10] = (n < 7) ? 1.f : 0.f;
  f[11] = (n == 7) ? 1.f : 0.f;
  f[12] = (n == 8) ? 1.f : 0.f;
  f[13] = fabsf((float)(n - 7));
  const float* w = &encW[((size_t)n * 128 + d) * 14];
  float s = encb[n * 128 + d];
#pragma unroll
  for (int i = 0; i < 14; i++) s = fmaf(f[i], w[i], s);
  Xh[(size_t)v * LDX + d] = (_Float16)s;
}

// ---------------- fill ----------------
__global__ __launch_bounds__(256) void fill_kernel(const float* __restrict__ nf,
                                                   float* __restrict__ fill) {
  __shared__ float sx[256], sy[256], sz[256];
  int tid = threadIdx.x;
  float ax = 0.f, ay = 0.f, az = 0.f;
  for (int p = tid; p < BB * NN; p += 256) {
    int b = p / NN, n = p - b * NN;
    size_t late  = (((size_t)b * TT + (TT - 1)) * NN + n) * 10;
    size_t early = (((size_t)b * TT) * NN + n) * 10;
    ax += nf[late + 0] - nf[early + 0];
    ay += nf[late + 1] - nf[early + 1];
    az += nf[late + 2] - nf[early + 2];
  }
  sx[tid] = ax; sy[tid] = ay; sz[tid] = az;
  __syncthreads();
  for (int s = 128; s > 0; s >>= 1) {
    if (tid < s) { sx[tid] += sx[tid + s]; sy[tid] += sy[tid + s]; sz[tid] += sz[tid + s]; }
    __syncthreads();
  }
  if (tid == 0) { fill[0] = sx[0] / E_REAL; fill[1] = sy[0] / E_REAL; fill[2] = sz[0] / E_REAL; }
}

// ================= MFMA GEMM (R9-proven sync staging): 64 rows x 256 cols =================
#define LDA 40
struct GemmSh { _Float16 A[64 * LDA]; _Float16 B[256 * LDA]; };   // 5 KB + 20 KB

__device__ __forceinline__ void mfma_gemm(const _Float16* __restrict__ x,
    const _Float16* __restrict__ W, int K, int row0, int tid,
    _Float16* shA, _Float16* shB, f32x4 (&acc)[4][4]) {
  int lane = tid & 63, wv = tid >> 6;
  int quad = lane >> 4, mrow = lane & 15;
  int ar = tid >> 2, ak = (tid & 3) << 3;
  for (int k0 = 0; k0 < K; k0 += 32) {
    *(half8*)&shA[ar * LDA + ak] = *(const half8*)&x[(size_t)(row0 + ar) * LDX + k0 + ak];
#pragma unroll
    for (int j = 0; j < 4; j++)
      *(half8*)&shB[tid * LDA + (j << 3)] = *(const half8*)&W[(size_t)tid * K + k0 + (j << 3)];
    __syncthreads();
    half8 af[4], bfr[4];
#pragma unroll
    for (int rt = 0; rt < 4; rt++)
      af[rt] = *(const half8*)&shA[(rt * 16 + mrow) * LDA + quad * 8];
#pragma unroll
    for (int ct = 0; ct < 4; ct++)
      bfr[ct] = *(const half8*)&shB[(wv * 64 + ct * 16 + mrow) * LDA + quad * 8];
#pragma unroll
    for (int rt = 0; rt < 4; rt++)
#pragma unroll
      for (int ct = 0; ct < 4; ct++)
        acc[rt][ct] = __builtin_amdgcn_mfma_f32_16x16x32_f16(af[rt], bfr[ct], acc[rt][ct], 0, 0, 0);
    __syncthreads();
  }
}

// dual-B variant: stages A once, both rW and sW tiles; 32 MFMA per barrier pair
struct GemmSh2 { _Float16 A[64 * LDA]; _Float16 Br[256 * LDA]; _Float16 Bs[256 * LDA]; }; // 45 KB

__device__ __forceinline__ void mfma_gemm2(const _Float16* __restrict__ x,
    const _Float16* __restrict__ Wr, const _Float16* __restrict__ Ws, int K, int row0, int tid,
    _Float16* shA, _Float16* shBr, _Float16* shBs,
    f32x4 (&accr)[4][4], f32x4 (&accs)[4][4]) {
  int lane = tid & 63, wv = tid >> 6;
  int quad = lane >> 4, mrow = lane & 15;
  int ar = tid >> 2, ak = (tid & 3) << 3;
  for (int k0 = 0; k0 < K; k0 += 32) {
    *(half8*)&shA[ar * LDA + ak] = *(const half8*)&x[(size_t)(row0 + ar) * LDX + k0 + ak];
#pragma unroll
    for (int j = 0; j < 4; j++) {
      *(half8*)&shBr[tid * LDA + (j << 3)] = *(const half8*)&Wr[(size_t)tid * K + k0 + (j << 3)];
      *(half8*)&shBs[tid * LDA + (j << 3)] = *(const half8*)&Ws[(size_t)tid * K + k0 + (j << 3)];
    }
    __syncthreads();
    half8 af[4], br[4], bs[4];
#pragma unroll
    for (int rt = 0; rt < 4; rt++)
      af[rt] = *(const half8*)&shA[(rt * 16 + mrow) * LDA + quad * 8];
#pragma unroll
    for (int ct = 0; ct < 4; ct++) {
      br[ct] = *(const half8*)&shBr[(wv * 64 + ct * 16 + mrow) * LDA + quad * 8];
      bs[ct] = *(const half8*)&shBs[(wv * 64 + ct * 16 + mrow) * LDA + quad * 8];
    }
#pragma unroll
    for (int rt = 0; rt < 4; rt++)
#pragma unroll
      for (int ct = 0; ct < 4; ct++) {
        accr[rt][ct] = __builtin_amdgcn_mfma_f32_16x16x32_f16(af[rt], br[ct], accr[rt][ct], 0, 0, 0);
        accs[rt][ct] = __builtin_amdgcn_mfma_f32_16x16x32_f16(af[rt], bs[ct], accs[rt][ct], 0, 0, 0);
      }
    __syncthreads();
  }
}

// write ACC (+bias) into epilogue LDS buffer as bf16.  C/D map: col=lane&15, row=quad*4+reg
#define ACC_TO_EPI(EPI, BIASPTR, ACC)                                           \
  {                                                                             \
    int lane_ = tid & 63, wv_ = tid >> 6, quad_ = lane_ >> 4, mrow_ = lane_ & 15; \
    _Pragma("unroll")                                                           \
    for (int rt = 0; rt < 4; rt++)                                              \
      _Pragma("unroll")                                                         \
      for (int ct = 0; ct < 4; ct++) {                                          \
        int col = wv_ * 64 + ct * 16 + mrow_;                                   \
        float bs_ = BIASPTR[col];                                               \
        _Pragma("unroll")                                                       \
        for (int r = 0; r < 4; r++)                                             \
          EPI[rt * 16 + quad_ * 4 + r][col] = f2bf(ACC[rt][ct][r] + bs_);       \
      }                                                                         \
  }                                                                             \
  __syncthreads();

// ---------------- XL = X @ lW.T + lb -> bf16 ----------------
__global__ __launch_bounds__(256) void gemm_xl_kernel(const _Float16* __restrict__ x, int K,
    const _Float16* __restrict__ W, const float* __restrict__ bias, bf16* __restrict__ XL) {
  __shared__ union { GemmSh st; unsigned short epi[64][264]; } sh;
  int tid = threadIdx.x;
  int row0 = blockIdx.x * 64;
  f32x4 acc[4][4] = {};
  mfma_gemm(x, W, K, row0, tid, sh.st.A, sh.st.B, acc);
  ACC_TO_EPI(sh.epi, bias, acc)
  int r = tid >> 2;
#pragma unroll
  for (int j = 0; j < 16; j++) {
    int c0 = (((tid & 3) << 4) + j) << 2;
    *(ushort4*)&XL[(size_t)(row0 + r) * LDX + c0] = *(const ushort4*)&sh.epi[r][c0];
  }
}

// ---------------- FUSED: XR+XO GEMMs, logits+softmax (wbuf in LDS), aggregate+LN+SiLU ----------------
struct LoSh {
  union {
    GemmSh2 st;                      // 45 KB (GEMM phase)
    unsigned short epi[64][264];     // 33.8 KB (epilogue phases)
  } u;
  float wsm[64][16];                 // per-node per-head edge weights (4 KB)
};

__global__ __launch_bounds__(256) void lo_kernel(_Float16* Xh, int K,
    const _Float16* __restrict__ rW, const float* __restrict__ rb,
    const _Float16* __restrict__ sW, const float* __restrict__ sb,
    const bf16* __restrict__ XL, const float* __restrict__ nf, const float* __restrict__ fill,
    const float* __restrict__ att, const float* __restrict__ eW,
    const float* __restrict__ gamma, const float* __restrict__ beta) {
  __shared__ LoSh sh;
  int tid = threadIdx.x;
  int row0 = blockIdx.x * 64;
  f32x4 accr[4][4] = {}, accs[4][4] = {};
  mfma_gemm2(Xh, rW, sW, K, row0, tid, sh.u.st.A, sh.u.st.Br, sh.u.st.Bs, accr, accs);

  // ---- phase 1: XR -> epi, compute softmax weights -> wsm ----
  ACC_TO_EPI(sh.u.epi, rb, accr)
  int wave = tid >> 6, lane = tid & 63;
  int cc = lane << 2;          // 4 channels/lane; 16 lanes = one head
  int h = lane >> 4;
  float attv[4], ew[4][3];
#pragma unroll
  for (int i = 0; i < 4; i++) {
    attv[i] = att[cc + i];
    ew[i][0] = eW[(cc + i) * 3 + 0];
    ew[i][1] = eW[(cc + i) * 3 + 1];
    ew[i][2] = eW[(cc + i) * 3 + 2];
  }
  float f0 = fill[0], f1 = fill[1], f2 = fill[2];
  for (int k = 0; k < 16; k++) {
    int v = row0 + wave * 16 + k;
    int n = v % NN;
    int t = (v / NN) & 63;
    int srcs[4] = { v, (n > 0) ? v - 1 : v, (n < NN - 1) ? v + 1 : v, (t > 0) ? v - NN : v };
    bool valid[4] = { true, n > 0, n < NN - 1, t > 0 };
    float px = nf[(size_t)v * 10 + 0];
    float py = nf[(size_t)v * 10 + 1];
    float pz = nf[(size_t)v * 10 + 2];
    ushort4 xr4 = *(const ushort4*)&sh.u.epi[wave * 16 + k][cc];
    float xr[4] = { bfdec(xr4.x), bfdec(xr4.y), bfdec(xr4.z), bfdec(xr4.w) };
    float logit[4];
#pragma unroll
    for (int e = 0; e < 4; e++) {
      int s = srcs[e];
      float a0, a1, a2;
      if (e == 0) { a0 = f0; a1 = f1; a2 = f2; }
      else {
        a0 = px - nf[(size_t)s * 10 + 0];
        a1 = py - nf[(size_t)s * 10 + 1];
        a2 = pz - nf[(size_t)s * 10 + 2];
      }
      float4 xl = ldbf4(&XL[(size_t)s * LDX + cc]);
      float xlv[4] = { xl.x, xl.y, xl.z, xl.w };
      float p = 0.f;
#pragma unroll
      for (int i = 0; i < 4; i++) {
        float em = fmaf(ew[i][0], a0, fmaf(ew[i][1], a1, ew[i][2] * a2));
        float mv = xlv[i] + xr[i] + em;
        mv = (mv > 0.f) ? mv : 0.2f * mv;   // leaky_relu 0.2
        p = fmaf(mv, attv[i], p);
      }
      p += __shfl_xor(p, 1); p += __shfl_xor(p, 2); p += __shfl_xor(p, 4); p += __shfl_xor(p, 8);
      logit[e] = valid[e] ? p : -1e30f;
    }
    float mx = fmaxf(fmaxf(logit[0], logit[1]), fmaxf(logit[2], logit[3]));
    float wv4[4], wsum = 0.f;
#pragma unroll
    for (int e = 0; e < 4; e++) { wv4[e] = __expf(logit[e] - mx); wsum += wv4[e]; }
    float inv = 1.f / wsum;
    if ((lane & 15) == 0) {
      float4 w4 = { wv4[0] * inv, wv4[1] * inv, wv4[2] * inv, wv4[3] * inv };
      *(float4*)&sh.wsm[wave * 16 + k][h * 4] = w4;
    }
  }
  __syncthreads();   // all waves done with epi(XR) + wsm visible

  // ---- phase 2: XO -> epi, aggregate + LayerNorm + SiLU, in-place X ----
  ACC_TO_EPI(sh.u.epi, sb, accs)
  float gm[4], bt[4];
#pragma unroll
  for (int i = 0; i < 4; i++) { gm[i] = gamma[cc + i]; bt[i] = beta[cc + i]; }
  for (int k = 0; k < 16; k++) {
    int v = row0 + wave * 16 + k;
    int n = v % NN;
    int t = (v / NN) & 63;
    int srcs[4] = { v, (n > 0) ? v - 1 : v, (n < NN - 1) ? v + 1 : v, (t > 0) ? v - NN : v };
    float4 w4 = *(const float4*)&sh.wsm[wave * 16 + k][h * 4];
    float wv4[4] = { w4.x, w4.y, w4.z, w4.w };   // invalid edges have weight exactly 0
    ushort4 xo4 = *(const ushort4*)&sh.u.epi[wave * 16 + k][cc];
    float xv[4] = { bfdec(xo4.x), bfdec(xo4.y), bfdec(xo4.z), bfdec(xo4.w) };
#pragma unroll
    for (int e = 0; e < 4; e++) {
      float4 xl = ldbf4(&XL[(size_t)srcs[e] * LDX + cc]);
      xv[0] = fmaf(wv4[e], xl.x, xv[0]);
      xv[1] = fmaf(wv4[e], xl.y, xv[1]);
      xv[2] = fmaf(wv4[e], xl.z, xv[2]);
      xv[3] = fmaf(wv4[e], xl.w, xv[3]);
    }
    float s1 = xv[0] + xv[1] + xv[2] + xv[3];
#pragma unroll
    for (int off = 1; off < 64; off <<= 1) s1 += __shfl_xor(s1, off);
    float mu = s1 * (1.f / 256.f);
    float s2 = 0.f;
#pragma unroll
    for (int i = 0; i < 4; i++) { float d = xv[i] - mu; s2 = fmaf(d, d, s2); }
#pragma unroll
    for (int off = 1; off < 64; off <<= 1) s2 += __shfl_xor(s2, off);
    float rs = rsqrtf(s2 * (1.f / 256.f) + 1e-5f);
    half4 o;
#pragma unroll
    for (int i = 0; i < 4; i++) {
      float y = (xv[i] - mu) * rs * gm[i] + bt[i];
      o[i] = (_Float16)(y * (1.f / (1.f + __expf(-y))));   // SiLU
    }
    *(half4*)&Xh[(size_t)v * LDX + cc] = o;
  }
}

// ---------------- mean over 576 positions -> (B,256) fp32 ----------------
__global__ __launch_bounds__(256) void pool_kernel(const _Float16* __restrict__ Xh,
                                                   float* __restrict__ out) {
  int b = blockIdx.x, c = threadIdx.x;
  const _Float16* p = &Xh[(size_t)b * 576 * LDX + c];
  float s = 0.f;
  for (int i = 0; i < 576; i++) s += (float)p[(size_t)i * LDX];
  out[b * 256 + c] = s * (1.f / 576.f);
}

extern "C" void kernel_launch(void* const* d_in, const int* in_sizes, int n_in,
                              void* d_out, int out_size, void* d_ws, size_t ws_size,
                              hipStream_t stream) {
  static const int kSize[NARR] = {
    737280, 16128, 1152,
    32768, 256, 32768, 256, 256, 768, 32768, 256, 256, 256,   // layer 0 (K=128)
    65536, 256, 65536, 256, 256, 768, 65536, 256, 256, 256,   // layer 1 (K=256)
    65536, 256, 65536, 256, 256, 768, 65536, 256, 256, 256    // layer 2 (K=256)
  };
  if (n_in != NARR || out_size != BB * 256) return;
  for (int i = 0; i < NARR; i++) if (in_sizes[i] != kSize[i]) return;

  CvtArgs ca;
  int off = 0;
  for (int i = 0; i < NARR; i++) { ca.src[i] = d_in[i]; ca.size[i] = kSize[i]; ca.off[i] = off; off += kSize[i]; }
  const int PRM_ELEMS = off;   // 1,252,992

  const size_t OFF_FLAG = 0;
  const size_t OFF_FILL = 16;
  const size_t OFF_PRM  = 256;
  const size_t OFF_PRMH = OFF_PRM + (size_t)PRM_ELEMS * 4;     // f16 shadow
  const size_t OFF_XL   = OFF_PRMH + (size_t)PRM_ELEMS * 2;
  const size_t OFF_XH   = OFF_XL + (size_t)NODES * LDX * 2;    // XL bf16
  const size_t NEED     = OFF_XH + (size_t)NODES * LDX * 2;    // ~83 MiB (proven fit)
  if (ws_size < NEED) return;

  char* ws = (char*)d_ws;
  float*     flag = (float*)(ws + OFF_FLAG);
  float*     fill = (float*)(ws + OFF_FILL);
  float*     prm  = (float*)(ws + OFF_PRM);
  _Float16*  prmh = (_Float16*)(ws + OFF_PRMH);
  bf16*      XL   = (bf16*)(ws + OFF_XL);
  _Float16*  Xh   = (_Float16*)(ws + OFF_XH);

  detect_kernel<<<1, 256, 0, stream>>>((const unsigned short*)d_in[0], flag);
  convert_kernel<<<dim3(360, NARR), 256, 0, stream>>>(ca, flag, prm);
  tohalf_kernel<<<(PRM_ELEMS + 255) / 256, 256, 0, stream>>>(prm, prmh, PRM_ELEMS);

  const float* nf   = prm + ca.off[0];
  const float* encW = prm + ca.off[1];
  const float* encb = prm + ca.off[2];

  encoder_simple<<<NODES, 128, 0, stream>>>(nf, encW, encb, Xh);
  fill_kernel<<<1, 256, 0, stream>>>(nf, fill);

  int K = 128;
  for (int L = 0; L < 3; L++) {
    const _Float16* lWh = prmh + ca.off[3 + L * 10 + 0];
    const float*    lb  = prm  + ca.off[3 + L * 10 + 1];
    const _Float16* rWh = prmh + ca.off[3 + L * 10 + 2];
    const float*    rb  = prm  + ca.off[3 + L * 10 + 3];
    const float*    att = prm  + ca.off[3 + L * 10 + 4];
    const float*    eW  = prm  + ca.off[3 + L * 10 + 5];
    const _Float16* sWh = prmh + ca.off[3 + L * 10 + 6];
    const float*    sb  = prm  + ca.off[3 + L * 10 + 7];
    const float*    g   = prm  + ca.off[3 + L * 10 + 8];
    const float*    b   = prm  + ca.off[3 + L * 10 + 9];
    gemm_xl_kernel<<<NODES / 64, 256, 0, stream>>>(Xh, K, lWh, lb, XL);
    lo_kernel<<<NODES / 64, 256, 0, stream>>>(Xh, K, rWh, rb, sWh, sb, XL, nf, fill,
                                              att, eW, g, b);
    K = 256;
  }
  pool_kernel<<<BB, 256, 0, stream>>>(Xh, (float*)d_out);
}

// Round 12
// 754.987 us; speedup vs baseline: 1.2545x; 1.2545x over previous
//
#include <hip/hip_runtime.h>
#include <hip/hip_bf16.h>
#include <math.h>

#define NODES 73728   // B*T*N = 128*64*9
#define BB    128
#define TT    64
#define NN    9
#define LDX   256
#define E_REAL 203648.0f
#define NARR  33

typedef __hip_bfloat16 bf16;
typedef _Float16 half8 __attribute__((ext_vector_type(8)));
typedef _Float16 half4 __attribute__((ext_vector_type(4)));
typedef float f32x4 __attribute__((ext_vector_type(4)));

__device__ __forceinline__ float bfdec(unsigned short u) {
  return __uint_as_float(((unsigned)u) << 16);
}
__device__ __forceinline__ unsigned short f2bf(float x) {
  bf16 h = __float2bfloat16(x);
  return *(unsigned short*)&h;
}
__device__ __forceinline__ float4 ldbf4(const bf16* p) {  // 8B-aligned
  ushort4 u = *(const ushort4*)p;
  float4 f;
  f.x = bfdec(u.x); f.y = bfdec(u.y); f.z = bfdec(u.z); f.w = bfdec(u.w);
  return f;
}

// ---------------- dtype detector ----------------
__global__ __launch_bounds__(256) void detect_kernel(const unsigned short* __restrict__ raw,
                                                     float* __restrict__ flag) {
  __shared__ float sm[256];
  float mx = 0.f;
  for (int i = threadIdx.x; i < 2048; i += 256) mx = fmaxf(mx, fabsf(bfdec(raw[2 * i])));
  sm[threadIdx.x] = mx;
  __syncthreads();
  for (int s = 128; s > 0; s >>= 1) {
    if (threadIdx.x < s) sm[threadIdx.x] = fmaxf(sm[threadIdx.x], sm[threadIdx.x + s]);
    __syncthreads();
  }
  if (threadIdx.x == 0) flag[0] = (sm[0] > 1000.f) ? 1.f : 0.f;
}

// ---------------- convert all inputs to fp32 params region ----------------
struct CvtArgs { const void* src[NARR]; int size[NARR]; int off[NARR]; };

__global__ __launch_bounds__(256) void convert_kernel(CvtArgs a, const float* __restrict__ flag,
                                                      float* __restrict__ dst) {
  int i = blockIdx.y;
  int sz = a.size[i];
  bool isf32 = flag[0] > 0.5f;
  const float* sf = (const float*)a.src[i];
  const unsigned short* sh = (const unsigned short*)a.src[i];
  float* d = dst + a.off[i];
  for (int j = blockIdx.x * 256 + threadIdx.x; j < sz; j += gridDim.x * 256)
    d[j] = isf32 ? sf[j] : bfdec(sh[j]);
}

// ---------------- f16 shadow of the whole param region ----------------
__global__ __launch_bounds__(256) void tohalf_kernel(const float* __restrict__ prm,
                                                     _Float16* __restrict__ dst, int n) {
  int i = blockIdx.x * 256 + threadIdx.x;
  if (i < n) dst[i] = (_Float16)prm[i];
}

// ---------------- encoder (R9-proven: one block per node, thread d) ----------------
__global__ __launch_bounds__(128) void encoder_simple(const float* __restrict__ nf,
    const float* __restrict__ encW, const float* __restrict__ encb, _Float16* __restrict__ Xh) {
  int v = blockIdx.x, d = threadIdx.x, n = v % NN;
  float f[14];
#pragma unroll
  for (int i = 0; i < 10; i++) f[i] = nf[(size_t)v * 10 + i];
  f[10] = (n < 7) ? 1.f : 0.f;
  f[11] = (n == 7) ? 1.f : 0.f;
  f[12] = (n == 8) ? 1.f : 0.f;
  f[13] = fabsf((float)(n - 7));
  const float* w = &encW[((size_t)n * 128 + d) * 14];
  float s = encb[n * 128 + d];
#pragma unroll
  for (int i = 0; i < 14; i++) s = fmaf(f[i], w[i], s);
  Xh[(size_t)v * LDX + d] = (_Float16)s;
}

// ---------------- fill ----------------
__global__ __launch_bounds__(256) void fill_kernel(const float* __restrict__ nf,
                                                   float* __restrict__ fill) {
  __shared__ float sx[256], sy[256], sz[256];
  int tid = threadIdx.x;
  float ax = 0.f, ay = 0.f, az = 0.f;
  for (int p = tid; p < BB * NN; p += 256) {
    int b = p / NN, n = p - b * NN;
    size_t late  = (((size_t)b * TT + (TT - 1)) * NN + n) * 10;
    size_t early = (((size_t)b * TT) * NN + n) * 10;
    ax += nf[late + 0] - nf[early + 0];
    ay += nf[late + 1] - nf[early + 1];
    az += nf[late + 2] - nf[early + 2];
  }
  sx[tid] = ax; sy[tid] = ay; sz[tid] = az;
  __syncthreads();
  for (int s = 128; s > 0; s >>= 1) {
    if (tid < s) { sx[tid] += sx[tid + s]; sy[tid] += sy[tid + s]; sz[tid] += sz[tid + s]; }
    __syncthreads();
  }
  if (tid == 0) { fill[0] = sx[0] / E_REAL; fill[1] = sy[0] / E_REAL; fill[2] = sz[0] / E_REAL; }
}

// ================= MFMA GEMM (R9-proven sync staging): 64 rows x 256 cols =================
#define LDA 40
#define EPC 268   // epi row stride (ushorts): 536 B -> quad rows hit distinct bank sets
struct GemmSh { _Float16 A[64 * LDA]; _Float16 B[256 * LDA]; };   // 25.6 KB
union ShU { GemmSh st; unsigned short epi[32][EPC]; };            // union = 25.6 KB -> 6 blk/CU

__device__ __forceinline__ void mfma_gemm(const _Float16* __restrict__ x,
    const _Float16* __restrict__ W, int K, int row0, int tid,
    _Float16* shA, _Float16* shB, f32x4 (&acc)[4][4]) {
  int lane = tid & 63, wv = tid >> 6;
  int quad = lane >> 4, mrow = lane & 15;
  int ar = tid >> 2, ak = (tid & 3) << 3;
  for (int k0 = 0; k0 < K; k0 += 32) {
    *(half8*)&shA[ar * LDA + ak] = *(const half8*)&x[(size_t)(row0 + ar) * LDX + k0 + ak];
#pragma unroll
    for (int j = 0; j < 4; j++)
      *(half8*)&shB[tid * LDA + (j << 3)] = *(const half8*)&W[(size_t)tid * K + k0 + (j << 3)];
    __syncthreads();
    half8 af[4], bfr[4];
#pragma unroll
    for (int rt = 0; rt < 4; rt++)
      af[rt] = *(const half8*)&shA[(rt * 16 + mrow) * LDA + quad * 8];
#pragma unroll
    for (int ct = 0; ct < 4; ct++)
      bfr[ct] = *(const half8*)&shB[(wv * 64 + ct * 16 + mrow) * LDA + quad * 8];
#pragma unroll
    for (int rt = 0; rt < 4; rt++)
#pragma unroll
      for (int ct = 0; ct < 4; ct++)
        acc[rt][ct] = __builtin_amdgcn_mfma_f32_16x16x32_f16(af[rt], bfr[ct], acc[rt][ct], 0, 0, 0);
    __syncthreads();
  }
}

// write acc row-tiles {2*CH, 2*CH+1} (+bias) into 32-row epi as bf16.
// C/D map: col=lane&15, local row = i*16 + quad*4 + reg
#define ACC_TO_EPI32(EPI, BIASPTR, ACC, CH)                                     \
  {                                                                             \
    int lane_ = tid & 63, wv_ = tid >> 6, quad_ = lane_ >> 4, mrow_ = lane_ & 15; \
    _Pragma("unroll")                                                           \
    for (int i_ = 0; i_ < 2; i_++) {                                            \
      int rt_ = (CH) * 2 + i_;                                                  \
      _Pragma("unroll")                                                         \
      for (int ct = 0; ct < 4; ct++) {                                          \
        int col = wv_ * 64 + ct * 16 + mrow_;                                   \
        float bs_ = BIASPTR[col];                                               \
        _Pragma("unroll")                                                       \
        for (int r = 0; r < 4; r++)                                             \
          EPI[i_ * 16 + quad_ * 4 + r][col] = f2bf(ACC[rt_][ct][r] + bs_);      \
      }                                                                         \
    }                                                                           \
  }                                                                             \
  __syncthreads();

// ---------------- XL = X @ lW.T + lb -> bf16 ----------------
__global__ __launch_bounds__(256, 5) void gemm_xl_kernel(const _Float16* __restrict__ x, int K,
    const _Float16* __restrict__ W, const float* __restrict__ bias, bf16* __restrict__ XL) {
  __shared__ ShU sh;
  int tid = threadIdx.x;
  int row0 = blockIdx.x * 64;
  f32x4 acc[4][4] = {};
  mfma_gemm(x, W, K, row0, tid, sh.st.A, sh.st.B, acc);
#pragma unroll
  for (int ch = 0; ch < 2; ch++) {
    ACC_TO_EPI32(sh.epi, bias, acc, ch)
    int r = tid >> 3;                       // 32 rows, 8 threads/row
#pragma unroll
    for (int j = 0; j < 8; j++) {
      int c0 = (((tid & 7) << 3) + j) << 2;
      *(ushort4*)&XL[(size_t)(row0 + ch * 32 + r) * LDX + c0] = *(const ushort4*)&sh.epi[r][c0];
    }
    __syncthreads();                        // reads done before next chunk overwrites
  }
}

// ---------------- fused: XR GEMM + edge logits + softmax -> wbuf[v][h][e] ----------------
__global__ __launch_bounds__(256, 5) void logits_kernel(const _Float16* __restrict__ x, int K,
    const _Float16* __restrict__ rW, const float* __restrict__ rb,
    const bf16* __restrict__ XL, const float* __restrict__ nf, const float* __restrict__ fill,
    const float* __restrict__ att, const float* __restrict__ eW, float* __restrict__ wbuf) {
  __shared__ ShU sh;
  int tid = threadIdx.x;
  int row0 = blockIdx.x * 64;
  f32x4 acc[4][4] = {};
  mfma_gemm(x, rW, K, row0, tid, sh.st.A, sh.st.B, acc);

  int wave = tid >> 6, lane = tid & 63;
  int cc = lane << 2;        // 4 channels/lane; 16 lanes = one head
  int h = lane >> 4;
  float attv[4], ew[4][3];
#pragma unroll
  for (int i = 0; i < 4; i++) {
    attv[i] = att[cc + i];
    ew[i][0] = eW[(cc + i) * 3 + 0];
    ew[i][1] = eW[(cc + i) * 3 + 1];
    ew[i][2] = eW[(cc + i) * 3 + 2];
  }
  float f0 = fill[0], f1 = fill[1], f2 = fill[2];
#pragma unroll
  for (int ch = 0; ch < 2; ch++) {
    ACC_TO_EPI32(sh.epi, rb, acc, ch)
    for (int k = 0; k < 8; k++) {
      int lr = wave * 8 + k;
      int v = row0 + ch * 32 + lr;
      int n = v % NN;
      int t = (v / NN) & 63;
      int srcs[4] = { v, (n > 0) ? v - 1 : v, (n < NN - 1) ? v + 1 : v, (t > 0) ? v - NN : v };
      bool valid[4] = { true, n > 0, n < NN - 1, t > 0 };
      float px = nf[(size_t)v * 10 + 0];
      float py = nf[(size_t)v * 10 + 1];
      float pz = nf[(size_t)v * 10 + 2];
      ushort4 xr4 = *(const ushort4*)&sh.epi[lr][cc];
      float xr[4] = { bfdec(xr4.x), bfdec(xr4.y), bfdec(xr4.z), bfdec(xr4.w) };
      float logit[4];
#pragma unroll
      for (int e = 0; e < 4; e++) {
        int s = srcs[e];
        float a0, a1, a2;
        if (e == 0) { a0 = f0; a1 = f1; a2 = f2; }
        else {
          a0 = px - nf[(size_t)s * 10 + 0];
          a1 = py - nf[(size_t)s * 10 + 1];
          a2 = pz - nf[(size_t)s * 10 + 2];
        }
        float4 xl = ldbf4(&XL[(size_t)s * LDX + cc]);
        float xlv[4] = { xl.x, xl.y, xl.z, xl.w };
        float p = 0.f;
#pragma unroll
        for (int i = 0; i < 4; i++) {
          float em = fmaf(ew[i][0], a0, fmaf(ew[i][1], a1, ew[i][2] * a2));
          float mv = xlv[i] + xr[i] + em;
          mv = (mv > 0.f) ? mv : 0.2f * mv;   // leaky_relu 0.2
          p = fmaf(mv, attv[i], p);
        }
        p += __shfl_xor(p, 1); p += __shfl_xor(p, 2); p += __shfl_xor(p, 4); p += __shfl_xor(p, 8);
        logit[e] = valid[e] ? p : -1e30f;
      }
      float mx = fmaxf(fmaxf(logit[0], logit[1]), fmaxf(logit[2], logit[3]));
      float wv4[4], wsum = 0.f;
#pragma unroll
      for (int e = 0; e < 4; e++) { wv4[e] = __expf(logit[e] - mx); wsum += wv4[e]; }
      float inv = 1.f / wsum;
      if ((lane & 15) == 0) {
        float4 w4 = { wv4[0] * inv, wv4[1] * inv, wv4[2] * inv, wv4[3] * inv };
        *(float4*)&wbuf[(size_t)v * 16 + h * 4] = w4;   // layout [v][h][e]
      }
    }
    __syncthreads();
  }
}

// ---------------- fused: XO = X@sW.T + bias + sum_e w*XL[src]; LN; SiLU; X f16 in-place ----------------
__global__ __launch_bounds__(256, 5) void out_kernel(_Float16* Xh, int K,
    const _Float16* __restrict__ sW, const float* __restrict__ bias,
    const bf16* __restrict__ XL, const float* __restrict__ wbuf,
    const float* __restrict__ gamma, const float* __restrict__ beta) {
  __shared__ ShU sh;
  int tid = threadIdx.x;
  int row0 = blockIdx.x * 64;
  f32x4 acc[4][4] = {};
  mfma_gemm(Xh, sW, K, row0, tid, sh.st.A, sh.st.B, acc);

  int wave = tid >> 6, lane = tid & 63;
  int cc = lane << 2;
  int h = lane >> 4;
  float gm[4], bt[4];
#pragma unroll
  for (int i = 0; i < 4; i++) { gm[i] = gamma[cc + i]; bt[i] = beta[cc + i]; }
#pragma unroll
  for (int ch = 0; ch < 2; ch++) {
    ACC_TO_EPI32(sh.epi, bias, acc, ch)
    for (int k = 0; k < 8; k++) {
      int lr = wave * 8 + k;
      int v = row0 + ch * 32 + lr;
      int n = v % NN;
      int t = (v / NN) & 63;
      int srcs[4] = { v, (n > 0) ? v - 1 : v, (n < NN - 1) ? v + 1 : v, (t > 0) ? v - NN : v };
      float4 w4 = *(const float4*)&wbuf[(size_t)v * 16 + h * 4];
      float wv4[4] = { w4.x, w4.y, w4.z, w4.w };   // invalid edges have weight exactly 0
      ushort4 xo4 = *(const ushort4*)&sh.epi[lr][cc];
      float xv[4] = { bfdec(xo4.x), bfdec(xo4.y), bfdec(xo4.z), bfdec(xo4.w) };
#pragma unroll
      for (int e = 0; e < 4; e++) {
        float4 xl = ldbf4(&XL[(size_t)srcs[e] * LDX + cc]);
        xv[0] = fmaf(wv4[e], xl.x, xv[0]);
        xv[1] = fmaf(wv4[e], xl.y, xv[1]);
        xv[2] = fmaf(wv4[e], xl.z, xv[2]);
        xv[3] = fmaf(wv4[e], xl.w, xv[3]);
      }
      // LayerNorm over 256 channels (full-wave shuffle reduce)
      float s1 = xv[0] + xv[1] + xv[2] + xv[3];
#pragma unroll
      for (int off = 1; off < 64; off <<= 1) s1 += __shfl_xor(s1, off);
      float mu = s1 * (1.f / 256.f);
      float s2 = 0.f;
#pragma unroll
      for (int i = 0; i < 4; i++) { float d = xv[i] - mu; s2 = fmaf(d, d, s2); }
#pragma unroll
      for (int off = 1; off < 64; off <<= 1) s2 += __shfl_xor(s2, off);
      float rs = rsqrtf(s2 * (1.f / 256.f) + 1e-5f);
      half4 o;
#pragma unroll
      for (int i = 0; i < 4; i++) {
        float y = (xv[i] - mu) * rs * gm[i] + bt[i];
        o[i] = (_Float16)(y * (1.f / (1.f + __expf(-y))));   // SiLU
      }
      *(half4*)&Xh[(size_t)v * LDX + cc] = o;
    }
    __syncthreads();
  }
}

// ---------------- mean over 576 positions -> (B,256) fp32 ----------------
__global__ __launch_bounds__(256) void pool_kernel(const _Float16* __restrict__ Xh,
                                                   float* __restrict__ out) {
  int b = blockIdx.x, c = threadIdx.x;
  const _Float16* p = &Xh[(size_t)b * 576 * LDX + c];
  float s = 0.f;
  for (int i = 0; i < 576; i++) s += (float)p[(size_t)i * LDX];
  out[b * 256 + c] = s * (1.f / 576.f);
}

extern "C" void kernel_launch(void* const* d_in, const int* in_sizes, int n_in,
                              void* d_out, int out_size, void* d_ws, size_t ws_size,
                              hipStream_t stream) {
  static const int kSize[NARR] = {
    737280, 16128, 1152,
    32768, 256, 32768, 256, 256, 768, 32768, 256, 256, 256,   // layer 0 (K=128)
    65536, 256, 65536, 256, 256, 768, 65536, 256, 256, 256,   // layer 1 (K=256)
    65536, 256, 65536, 256, 256, 768, 65536, 256, 256, 256    // layer 2 (K=256)
  };
  if (n_in != NARR || out_size != BB * 256) return;
  for (int i = 0; i < NARR; i++) if (in_sizes[i] != kSize[i]) return;

  CvtArgs ca;
  int off = 0;
  for (int i = 0; i < NARR; i++) { ca.src[i] = d_in[i]; ca.size[i] = kSize[i]; ca.off[i] = off; off += kSize[i]; }
  const int PRM_ELEMS = off;   // 1,252,992

  const size_t OFF_FLAG = 0;
  const size_t OFF_FILL = 16;
  const size_t OFF_PRM  = 256;
  const size_t OFF_PRMH = OFF_PRM + (size_t)PRM_ELEMS * 4;     // f16 shadow
  const size_t OFF_WB   = OFF_PRMH + (size_t)PRM_ELEMS * 2;
  const size_t OFF_XL   = OFF_WB + (size_t)NODES * 16 * 4;
  const size_t OFF_XH   = OFF_XL + (size_t)NODES * LDX * 2;    // XL bf16
  const size_t NEED     = OFF_XH + (size_t)NODES * LDX * 2;    // ~88 MiB (proven fit)
  if (ws_size < NEED) return;

  char* ws = (char*)d_ws;
  float*     flag = (float*)(ws + OFF_FLAG);
  float*     fill = (float*)(ws + OFF_FILL);
  float*     prm  = (float*)(ws + OFF_PRM);
  _Float16*  prmh = (_Float16*)(ws + OFF_PRMH);
  float*     wbuf = (float*)(ws + OFF_WB);
  bf16*      XL   = (bf16*)(ws + OFF_XL);
  _Float16*  Xh   = (_Float16*)(ws + OFF_XH);

  detect_kernel<<<1, 256, 0, stream>>>((const unsigned short*)d_in[0], flag);
  convert_kernel<<<dim3(360, NARR), 256, 0, stream>>>(ca, flag, prm);
  tohalf_kernel<<<(PRM_ELEMS + 255) / 256, 256, 0, stream>>>(prm, prmh, PRM_ELEMS);

  const float* nf   = prm + ca.off[0];
  const float* encW = prm + ca.off[1];
  const float* encb = prm + ca.off[2];

  encoder_simple<<<NODES, 128, 0, stream>>>(nf, encW, encb, Xh);
  fill_kernel<<<1, 256, 0, stream>>>(nf, fill);

  int K = 128;
  for (int L = 0; L < 3; L++) {
    const _Float16* lWh = prmh + ca.off[3 + L * 10 + 0];
    const float*    lb  = prm  + ca.off[3 + L * 10 + 1];
    const _Float16* rWh = prmh + ca.off[3 + L * 10 + 2];
    const float*    rb  = prm  + ca.off[3 + L * 10 + 3];
    const float*    att = prm  + ca.off[3 + L * 10 + 4];
    const float*    eW  = prm  + ca.off[3 + L * 10 + 5];
    const _Float16* sWh = prmh + ca.off[3 + L * 10 + 6];
    const float*    sb  = prm  + ca.off[3 + L * 10 + 7];
    const float*    g   = prm  + ca.off[3 + L * 10 + 8];
    const float*    b   = prm  + ca.off[3 + L * 10 + 9];
    gemm_xl_kernel<<<NODES / 64, 256, 0, stream>>>(Xh, K, lWh, lb, XL);
    logits_kernel<<<NODES / 64, 256, 0, stream>>>(Xh, K, rWh, rb, XL, nf, fill, att, eW, wbuf);
    out_kernel<<<NODES / 64, 256, 0, stream>>>(Xh, K, sWh, sb, XL, wbuf, g, b);
    K = 256;
  }
  pool_kernel<<<BB, 256, 0, stream>>>(Xh, (float*)d_out);
}

// Round 13
// 595.770 us; speedup vs baseline: 1.5898x; 1.2672x over previous
//
#include <hip/hip_runtime.h>
#include <hip/hip_bf16.h>
#include <math.h>

#define NODES 73728   // B*T*N = 128*64*9
#define BB    128
#define TT    64
#define NN    9
#define LDX   256
#define E_REAL 203648.0f
#define NARR  33

typedef __hip_bfloat16 bf16;
typedef _Float16 half8 __attribute__((ext_vector_type(8)));
typedef _Float16 half4 __attribute__((ext_vector_type(4)));
typedef float f32x4 __attribute__((ext_vector_type(4)));

__device__ __forceinline__ float bfdec(unsigned short u) {
  return __uint_as_float(((unsigned)u) << 16);
}
__device__ __forceinline__ unsigned short f2bf(float x) {
  bf16 h = __float2bfloat16(x);
  return *(unsigned short*)&h;
}
__device__ __forceinline__ float4 ldbf4(const bf16* p) {  // 8B-aligned
  ushort4 u = *(const ushort4*)p;
  float4 f;
  f.x = bfdec(u.x); f.y = bfdec(u.y); f.z = bfdec(u.z); f.w = bfdec(u.w);
  return f;
}

// ---------------- dtype detector ----------------
__global__ __launch_bounds__(256) void detect_kernel(const unsigned short* __restrict__ raw,
                                                     float* __restrict__ flag) {
  __shared__ float sm[256];
  float mx = 0.f;
  for (int i = threadIdx.x; i < 2048; i += 256) mx = fmaxf(mx, fabsf(bfdec(raw[2 * i])));
  sm[threadIdx.x] = mx;
  __syncthreads();
  for (int s = 128; s > 0; s >>= 1) {
    if (threadIdx.x < s) sm[threadIdx.x] = fmaxf(sm[threadIdx.x], sm[threadIdx.x + s]);
    __syncthreads();
  }
  if (threadIdx.x == 0) flag[0] = (sm[0] > 1000.f) ? 1.f : 0.f;
}

// ---------------- convert all inputs to fp32 params region ----------------
struct CvtArgs { const void* src[NARR]; int size[NARR]; int off[NARR]; };

__global__ __launch_bounds__(256) void convert_kernel(CvtArgs a, const float* __restrict__ flag,
                                                      float* __restrict__ dst) {
  int i = blockIdx.y;
  int sz = a.size[i];
  bool isf32 = flag[0] > 0.5f;
  const float* sf = (const float*)a.src[i];
  const unsigned short* sh = (const unsigned short*)a.src[i];
  float* d = dst + a.off[i];
  for (int j = blockIdx.x * 256 + threadIdx.x; j < sz; j += gridDim.x * 256)
    d[j] = isf32 ? sf[j] : bfdec(sh[j]);
}

// ---------------- f16 shadow of the whole param region ----------------
__global__ __launch_bounds__(256) void tohalf_kernel(const float* __restrict__ prm,
                                                     _Float16* __restrict__ dst, int n) {
  int i = blockIdx.x * 256 + threadIdx.x;
  if (i < n) dst[i] = (_Float16)prm[i];
}

// ---------------- encoder (R9-proven: one block per node, thread d) ----------------
__global__ __launch_bounds__(128) void encoder_simple(const float* __restrict__ nf,
    const float* __restrict__ encW, const float* __restrict__ encb, _Float16* __restrict__ Xh) {
  int v = blockIdx.x, d = threadIdx.x, n = v % NN;
  float f[14];
#pragma unroll
  for (int i = 0; i < 10; i++) f[i] = nf[(size_t)v * 10 + i];
  f[10] = (n < 7) ? 1.f : 0.f;
  f[11] = (n == 7) ? 1.f : 0.f;
  f[12] = (n == 8) ? 1.f : 0.f;
  f[13] = fabsf((float)(n - 7));
  const float* w = &encW[((size_t)n * 128 + d) * 14];
  float s = encb[n * 128 + d];
#pragma unroll
  for (int i = 0; i < 14; i++) s = fmaf(f[i], w[i], s);
  Xh[(size_t)v * LDX + d] = (_Float16)s;
}

// ---------------- fill ----------------
__global__ __launch_bounds__(256) void fill_kernel(const float* __restrict__ nf,
                                                   float* __restrict__ fill) {
  __shared__ float sx[256], sy[256], sz[256];
  int tid = threadIdx.x;
  float ax = 0.f, ay = 0.f, az = 0.f;
  for (int p = tid; p < BB * NN; p += 256) {
    int b = p / NN, n = p - b * NN;
    size_t late  = (((size_t)b * TT + (TT - 1)) * NN + n) * 10;
    size_t early = (((size_t)b * TT) * NN + n) * 10;
    ax += nf[late + 0] - nf[early + 0];
    ay += nf[late + 1] - nf[early + 1];
    az += nf[late + 2] - nf[early + 2];
  }
  sx[tid] = ax; sy[tid] = ay; sz[tid] = az;
  __syncthreads();
  for (int s = 128; s > 0; s >>= 1) {
    if (tid < s) { sx[tid] += sx[tid + s]; sy[tid] += sy[tid + s]; sz[tid] += sz[tid + s]; }
    __syncthreads();
  }
  if (tid == 0) { fill[0] = sx[0] / E_REAL; fill[1] = sy[0] / E_REAL; fill[2] = sz[0] / E_REAL; }
}

// ================= MFMA GEMM (R9-proven sync staging): 64 rows x 256 cols =================
#define LDA 40
struct GemmSh { _Float16 A[64 * LDA]; _Float16 B[256 * LDA]; };

__device__ __forceinline__ void mfma_gemm(const _Float16* __restrict__ x,
    const _Float16* __restrict__ W, int K, int row0, int tid,
    _Float16* shA, _Float16* shB, f32x4 (&acc)[4][4]) {
  int lane = tid & 63, wv = tid >> 6;
  int quad = lane >> 4, mrow = lane & 15;
  int ar = tid >> 2, ak = (tid & 3) << 3;
  for (int k0 = 0; k0 < K; k0 += 32) {
    *(half8*)&shA[ar * LDA + ak] = *(const half8*)&x[(size_t)(row0 + ar) * LDX + k0 + ak];
#pragma unroll
    for (int j = 0; j < 4; j++)
      *(half8*)&shB[tid * LDA + (j << 3)] = *(const half8*)&W[(size_t)tid * K + k0 + (j << 3)];
    __syncthreads();
    half8 af[4], bfr[4];
#pragma unroll
    for (int rt = 0; rt < 4; rt++)
      af[rt] = *(const half8*)&shA[(rt * 16 + mrow) * LDA + quad * 8];
#pragma unroll
    for (int ct = 0; ct < 4; ct++)
      bfr[ct] = *(const half8*)&shB[(wv * 64 + ct * 16 + mrow) * LDA + quad * 8];
#pragma unroll
    for (int rt = 0; rt < 4; rt++)
#pragma unroll
      for (int ct = 0; ct < 4; ct++)
        acc[rt][ct] = __builtin_amdgcn_mfma_f32_16x16x32_f16(af[rt], bfr[ct], acc[rt][ct], 0, 0, 0);
    __syncthreads();
  }
}

// write acc (+bias) into epilogue LDS buffer as bf16.  C/D map: col=lane&15, row=quad*4+reg
#define ACC_TO_EPI(EPI, BIASPTR)                                                \
  {                                                                             \
    int lane_ = tid & 63, wv_ = tid >> 6, quad_ = lane_ >> 4, mrow_ = lane_ & 15; \
    _Pragma("unroll")                                                           \
    for (int rt = 0; rt < 4; rt++)                                              \
      _Pragma("unroll")                                                         \
      for (int ct = 0; ct < 4; ct++) {                                          \
        int col = wv_ * 64 + ct * 16 + mrow_;                                   \
        float bs_ = BIASPTR[col];                                               \
        _Pragma("unroll")                                                       \
        for (int r = 0; r < 4; r++)                                             \
          EPI[rt * 16 + quad_ * 4 + r][col] = f2bf(acc[rt][ct][r] + bs_);       \
      }                                                                         \
  }                                                                             \
  __syncthreads();

// ---------------- XL = X @ lW.T + lb -> bf16 ----------------
__global__ __launch_bounds__(256) void gemm_xl_kernel(const _Float16* __restrict__ x, int K,
    const _Float16* __restrict__ W, const float* __restrict__ bias, bf16* __restrict__ XL) {
  __shared__ union { GemmSh st; unsigned short epi[64][264]; } sh;
  int tid = threadIdx.x;
  int row0 = blockIdx.x * 64;
  f32x4 acc[4][4] = {};
  mfma_gemm(x, W, K, row0, tid, sh.st.A, sh.st.B, acc);
  ACC_TO_EPI(sh.epi, bias)
  int r = tid >> 2;
#pragma unroll
  for (int j = 0; j < 16; j++) {
    int c0 = (((tid & 3) << 4) + j) << 2;
    *(ushort4*)&XL[(size_t)(row0 + r) * LDX + c0] = *(const ushort4*)&sh.epi[r][c0];
  }
}

// ---------------- fused: XR GEMM + edge logits + softmax + AGGREGATION -> AGG[v] bf16 ----------------
// AGG[v,c] = sum_e w_e * XL[src_e, c]  (the XL rows are loaded here anyway for the logits)
__global__ __launch_bounds__(256) void logits_kernel(const _Float16* __restrict__ x, int K,
    const _Float16* __restrict__ rW, const float* __restrict__ rb,
    const bf16* __restrict__ XL, const float* __restrict__ nf, const float* __restrict__ fill,
    const float* __restrict__ att, const float* __restrict__ eW, bf16* __restrict__ AGG) {
  __shared__ union { GemmSh st; unsigned short epi[64][264]; } sh;
  int tid = threadIdx.x;
  int row0 = blockIdx.x * 64;
  f32x4 acc[4][4] = {};
  mfma_gemm(x, rW, K, row0, tid, sh.st.A, sh.st.B, acc);
  ACC_TO_EPI(sh.epi, rb)

  int wave = tid >> 6, lane = tid & 63;
  int cc = lane << 2;        // 4 channels/lane; 16 lanes = one head
  float attv[4], ew[4][3];
#pragma unroll
  for (int i = 0; i < 4; i++) {
    attv[i] = att[cc + i];
    ew[i][0] = eW[(cc + i) * 3 + 0];
    ew[i][1] = eW[(cc + i) * 3 + 1];
    ew[i][2] = eW[(cc + i) * 3 + 2];
  }
  float f0 = fill[0], f1 = fill[1], f2 = fill[2];
  for (int k = 0; k < 16; k++) {
    int v = row0 + wave * 16 + k;
    int n = v % NN;
    int t = (v / NN) & 63;
    int srcs[4] = { v, (n > 0) ? v - 1 : v, (n < NN - 1) ? v + 1 : v, (t > 0) ? v - NN : v };
    bool valid[4] = { true, n > 0, n < NN - 1, t > 0 };
    float px = nf[(size_t)v * 10 + 0];
    float py = nf[(size_t)v * 10 + 1];
    float pz = nf[(size_t)v * 10 + 2];
    ushort4 xr4 = *(const ushort4*)&sh.epi[wave * 16 + k][cc];
    float xr[4] = { bfdec(xr4.x), bfdec(xr4.y), bfdec(xr4.z), bfdec(xr4.w) };
    float logit[4], xlv[4][4];
#pragma unroll
    for (int e = 0; e < 4; e++) {
      int s = srcs[e];
      float a0, a1, a2;
      if (e == 0) { a0 = f0; a1 = f1; a2 = f2; }
      else {
        a0 = px - nf[(size_t)s * 10 + 0];
        a1 = py - nf[(size_t)s * 10 + 1];
        a2 = pz - nf[(size_t)s * 10 + 2];
      }
      float4 xl = ldbf4(&XL[(size_t)s * LDX + cc]);
      xlv[e][0] = xl.x; xlv[e][1] = xl.y; xlv[e][2] = xl.z; xlv[e][3] = xl.w;
      float p = 0.f;
#pragma unroll
      for (int i = 0; i < 4; i++) {
        float em = fmaf(ew[i][0], a0, fmaf(ew[i][1], a1, ew[i][2] * a2));
        float mv = xlv[e][i] + xr[i] + em;
        mv = (mv > 0.f) ? mv : 0.2f * mv;   // leaky_relu 0.2
        p = fmaf(mv, attv[i], p);
      }
      p += __shfl_xor(p, 1); p += __shfl_xor(p, 2); p += __shfl_xor(p, 4); p += __shfl_xor(p, 8);
      logit[e] = valid[e] ? p : -1e30f;
    }
    float mx = fmaxf(fmaxf(logit[0], logit[1]), fmaxf(logit[2], logit[3]));
    float wv4[4], wsum = 0.f;
#pragma unroll
    for (int e = 0; e < 4; e++) { wv4[e] = __expf(logit[e] - mx); wsum += wv4[e]; }
    float inv = 1.f / wsum;
    float agg[4] = { 0.f, 0.f, 0.f, 0.f };
#pragma unroll
    for (int e = 0; e < 4; e++) {
      float w = wv4[e] * inv;                 // invalid edges: exactly 0
#pragma unroll
      for (int i = 0; i < 4; i++) agg[i] = fmaf(w, xlv[e][i], agg[i]);
    }
    ushort4 pk;
    pk.x = f2bf(agg[0]); pk.y = f2bf(agg[1]); pk.z = f2bf(agg[2]); pk.w = f2bf(agg[3]);
    *(ushort4*)&AGG[(size_t)v * LDX + cc] = pk;   // coalesced 8B/lane
  }
}

// ---------------- fused: XO = X@sW.T + bias + AGG; LN; SiLU; X f16 in-place ----------------
__global__ __launch_bounds__(256) void out_kernel(_Float16* Xh, int K,
    const _Float16* __restrict__ sW, const float* __restrict__ bias,
    const bf16* __restrict__ AGG,
    const float* __restrict__ gamma, const float* __restrict__ beta) {
  __shared__ union { GemmSh st; unsigned short epi[64][264]; } sh;
  int tid = threadIdx.x;
  int row0 = blockIdx.x * 64;
  f32x4 acc[4][4] = {};
  mfma_gemm(Xh, sW, K, row0, tid, sh.st.A, sh.st.B, acc);
  ACC_TO_EPI(sh.epi, bias)

  int wave = tid >> 6, lane = tid & 63;
  int cc = lane << 2;
  float gm[4], bt[4];
#pragma unroll
  for (int i = 0; i < 4; i++) { gm[i] = gamma[cc + i]; bt[i] = beta[cc + i]; }
  for (int k = 0; k < 16; k++) {
    int v = row0 + wave * 16 + k;
    ushort4 xo4 = *(const ushort4*)&sh.epi[wave * 16 + k][cc];
    float4 ag = ldbf4(&AGG[(size_t)v * LDX + cc]);   // one coalesced load replaces 4 gathers
    float xv[4] = { bfdec(xo4.x) + ag.x, bfdec(xo4.y) + ag.y,
                    bfdec(xo4.z) + ag.z, bfdec(xo4.w) + ag.w };
    // LayerNorm over 256 channels (full-wave shuffle reduce)
    float s1 = xv[0] + xv[1] + xv[2] + xv[3];
#pragma unroll
    for (int off = 1; off < 64; off <<= 1) s1 += __shfl_xor(s1, off);
    float mu = s1 * (1.f / 256.f);
    float s2 = 0.f;
#pragma unroll
    for (int i = 0; i < 4; i++) { float d = xv[i] - mu; s2 = fmaf(d, d, s2); }
#pragma unroll
    for (int off = 1; off < 64; off <<= 1) s2 += __shfl_xor(s2, off);
    float rs = rsqrtf(s2 * (1.f / 256.f) + 1e-5f);
    half4 o;
#pragma unroll
    for (int i = 0; i < 4; i++) {
      float y = (xv[i] - mu) * rs * gm[i] + bt[i];
      o[i] = (_Float16)(y * (1.f / (1.f + __expf(-y))));   // SiLU
    }
    *(half4*)&Xh[(size_t)v * LDX + cc] = o;
  }
}

// ---------------- mean over 576 positions -> (B,256) fp32 ----------------
__global__ __launch_bounds__(256) void pool_kernel(const _Float16* __restrict__ Xh,
                                                   float* __restrict__ out) {
  int b = blockIdx.x, c = threadIdx.x;
  const _Float16* p = &Xh[(size_t)b * 576 * LDX + c];
  float s = 0.f;
  for (int i = 0; i < 576; i++) s += (float)p[(size_t)i * LDX];
  out[b * 256 + c] = s * (1.f / 576.f);
}

extern "C" void kernel_launch(void* const* d_in, const int* in_sizes, int n_in,
                              void* d_out, int out_size, void* d_ws, size_t ws_size,
                              hipStream_t stream) {
  static const int kSize[NARR] = {
    737280, 16128, 1152,
    32768, 256, 32768, 256, 256, 768, 32768, 256, 256, 256,   // layer 0 (K=128)
    65536, 256, 65536, 256, 256, 768, 65536, 256, 256, 256,   // layer 1 (K=256)
    65536, 256, 65536, 256, 256, 768, 65536, 256, 256, 256    // layer 2 (K=256)
  };
  if (n_in != NARR || out_size != BB * 256) return;
  for (int i = 0; i < NARR; i++) if (in_sizes[i] != kSize[i]) return;

  CvtArgs ca;
  int off = 0;
  for (int i = 0; i < NARR; i++) { ca.src[i] = d_in[i]; ca.size[i] = kSize[i]; ca.off[i] = off; off += kSize[i]; }
  const int PRM_ELEMS = off;   // 1,252,992

  const size_t OFF_FLAG = 0;
  const size_t OFF_FILL = 16;
  const size_t OFF_PRM  = 256;
  const size_t OFF_PRMH = OFF_PRM + (size_t)PRM_ELEMS * 4;     // f16 shadow
  const size_t OFF_AGG  = OFF_PRMH + (size_t)PRM_ELEMS * 2;
  const size_t OFF_XL   = OFF_AGG + (size_t)NODES * LDX * 2;   // AGG bf16
  const size_t OFF_XH   = OFF_XL + (size_t)NODES * LDX * 2;    // XL bf16
  const size_t NEED     = OFF_XH + (size_t)NODES * LDX * 2;    // ~115 MiB (< proven 125.3)
  if (ws_size < NEED) return;

  char* ws = (char*)d_ws;
  float*     flag = (float*)(ws + OFF_FLAG);
  float*     fill = (float*)(ws + OFF_FILL);
  float*     prm  = (float*)(ws + OFF_PRM);
  _Float16*  prmh = (_Float16*)(ws + OFF_PRMH);
  bf16*      AGG  = (bf16*)(ws + OFF_AGG);
  bf16*      XL   = (bf16*)(ws + OFF_XL);
  _Float16*  Xh   = (_Float16*)(ws + OFF_XH);

  detect_kernel<<<1, 256, 0, stream>>>((const unsigned short*)d_in[0], flag);
  convert_kernel<<<dim3(360, NARR), 256, 0, stream>>>(ca, flag, prm);
  tohalf_kernel<<<(PRM_ELEMS + 255) / 256, 256, 0, stream>>>(prm, prmh, PRM_ELEMS);

  const float* nf   = prm + ca.off[0];
  const float* encW = prm + ca.off[1];
  const float* encb = prm + ca.off[2];

  encoder_simple<<<NODES, 128, 0, stream>>>(nf, encW, encb, Xh);
  fill_kernel<<<1, 256, 0, stream>>>(nf, fill);

  int K = 128;
  for (int L = 0; L < 3; L++) {
    const _Float16* lWh = prmh + ca.off[3 + L * 10 + 0];
    const float*    lb  = prm  + ca.off[3 + L * 10 + 1];
    const _Float16* rWh = prmh + ca.off[3 + L * 10 + 2];
    const float*    rb  = prm  + ca.off[3 + L * 10 + 3];
    const float*    att = prm  + ca.off[3 + L * 10 + 4];
    const float*    eW  = prm  + ca.off[3 + L * 10 + 5];
    const _Float16* sWh = prmh + ca.off[3 + L * 10 + 6];
    const float*    sb  = prm  + ca.off[3 + L * 10 + 7];
    const float*    g   = prm  + ca.off[3 + L * 10 + 8];
    const float*    b   = prm  + ca.off[3 + L * 10 + 9];
    gemm_xl_kernel<<<NODES / 64, 256, 0, stream>>>(Xh, K, lWh, lb, XL);
    logits_kernel<<<NODES / 64, 256, 0, stream>>>(Xh, K, rWh, rb, XL, nf, fill, att, eW, AGG);
    out_kernel<<<NODES / 64, 256, 0, stream>>>(Xh, K, sWh, sb, AGG, g, b);
    K = 256;
  }
  pool_kernel<<<BB, 256, 0, stream>>>(Xh, (float*)d_out);
}